// Round 15
// baseline (74.517 us; speedup 1.0000x reference)
//
#include <hip/hip_runtime.h>
#include <hip/hip_bf16.h>
#include <stdint.h>

#define NROWS 4096
#define DIMS  2048
#define BM    256
#define BKB   64              // K-tile = 64 int8 = 64 B rows
#define NTILES (DIMS / BKB)   // 32
#define NTB   (NROWS / BM)    // 16 -> 256 blocks
#define MARGIN_F 0.3f

typedef __attribute__((ext_vector_type(4))) int   i32x4;
typedef __attribute__((ext_vector_type(4))) float f32x4;

__device__ inline void atomicMaxF(float* addr, float v) {
  if (v >= 0.f) atomicMax((int*)addr, __float_as_int(v));
  else          atomicMin((unsigned int*)addr, __float_as_uint(v));
}
__device__ inline void atomicMinF(float* addr, float v) {
  if (v >= 0.f) atomicMin((int*)addr, __float_as_int(v));
  else          atomicMax((unsigned int*)addr, __float_as_uint(v));
}

// ------- normalize + per-row int8 quantization (q = rint(x*127/amax)) -------
__global__ __launch_bounds__(256) void norm_kernel(const float* __restrict__ in,
                                                   char* __restrict__ l2q,
                                                   float* __restrict__ recip,
                                                   float* __restrict__ dap,
                                                   float* __restrict__ dan) {
  int row = blockIdx.x;
  int t = threadIdx.x;
  const float4* rin = (const float4*)(in + (size_t)row * DIMS);
  float4 v0 = rin[t];
  float4 v1 = rin[t + 256];
  float ss = v0.x*v0.x + v0.y*v0.y + v0.z*v0.z + v0.w*v0.w
           + v1.x*v1.x + v1.y*v1.y + v1.z*v1.z + v1.w*v1.w;
  float am = fmaxf(fmaxf(fmaxf(fabsf(v0.x), fabsf(v0.y)), fmaxf(fabsf(v0.z), fabsf(v0.w))),
                   fmaxf(fmaxf(fabsf(v1.x), fabsf(v1.y)), fmaxf(fabsf(v1.z), fabsf(v1.w))));
  #pragma unroll
  for (int s = 1; s < 64; s <<= 1) {
    ss += __shfl_xor(ss, s);
    am = fmaxf(am, __shfl_xor(am, s));
  }
  __shared__ float wsum[4], wmax[4];
  if ((t & 63) == 0) { wsum[t >> 6] = ss; wmax[t >> 6] = am; }
  __syncthreads();
  float tot = wsum[0] + wsum[1] + wsum[2] + wsum[3];
  float amax = fmaxf(fmaxf(wmax[0], wmax[1]), fmaxf(wmax[2], wmax[3]));
  float rn = 1.0f / sqrtf(tot);
  float qs = 127.0f / amax;
  int q0 = (int)rintf(v0.x * qs), q1 = (int)rintf(v0.y * qs);
  int q2 = (int)rintf(v0.z * qs), q3 = (int)rintf(v0.w * qs);
  int q4 = (int)rintf(v1.x * qs), q5 = (int)rintf(v1.y * qs);
  int q6 = (int)rintf(v1.z * qs), q7 = (int)rintf(v1.w * qs);
  int p0 = (q0 & 255) | ((q1 & 255) << 8) | ((q2 & 255) << 16) | (q3 << 24);
  int p1 = (q4 & 255) | ((q5 & 255) << 8) | ((q6 & 255) << 16) | (q7 << 24);
  int* orow = (int*)(l2q + (size_t)row * DIMS);
  orow[t] = p0;
  orow[t + 256] = p1;
  if (t == 0) {
    recip[row] = amax * rn / 127.0f;
    dap[row] = -__builtin_inff();
    dan[row] = __builtin_inff();
  }
}

// ---------------- fused int8 GEMM (acc = Q . Q^T) + masked row max/min ----------------
// r12 structure with REGISTER STAGING instead of global_load_lds (the A/B
// test of the DMA path): per tile, 4 global_load_dwordx4 -> regs issued ~1
// tile ahead (T14 async-split: HBM/L2 latency hides under TILE_BODY); after
// the interior, 4 ds_write_b128 to the idle LDS set (linear 1KB/wave,
// conflict-free), lgkmcnt(0), one s_barrier per tile.
// LDS: 2 sets x (A 16KB + B 16KB) = 64 KB. Final LDS layout, chunk swizzle
// q = c ^ ((row>>1)&3), fragment reads, interior (12 ds_read_b128 + 32
// mfma_i32_16x16x64_i8 per wave), epilogue: byte-identical to r12
// (verified absmax 0, 0 bank conflicts).
__global__ __launch_bounds__(512) void gemm_reduce_kernel(
    const char* __restrict__ l2q, const int* __restrict__ tgt,
    const float* __restrict__ recip,
    float* __restrict__ dap, float* __restrict__ dan) {
  __shared__ __attribute__((aligned(16))) char ldsbuf[65536];  // 2 x (16K A + 16K B)

  // XCD-chunked bijective swizzle (256 blocks, 8 XCDs -> 32 contiguous per XCD)
  int c = blockIdx.x;
  int swz = (c & 7) * 32 + (c >> 3);
  int bi = swz >> 4, bj = swz & 15;

  int tid = threadIdx.x;
  int lane = tid & 63, w = tid >> 6;
  int wr = w >> 2;        // 0..1  (M half: 128 rows)
  int nc = w & 3;         // 0..3  (N quarter: 64 cols)

  i32x4 acc[8][4];
  #pragma unroll
  for (int m = 0; m < 8; m++)
    #pragma unroll
    for (int n = 0; n < 4; n++) acc[m][n] = (i32x4){0, 0, 0, 0};

  // --- staging source (r9/r12-identical addressing, now plain loads) ---
  int srow = tid >> 2;                               // 0..127
  int qq = (tid & 3) ^ ((tid >> 3) & 3);
  const char* gA = l2q + ((size_t)(bi * BM + srow)) * DIMS + qq * 16;
  const char* gB = l2q + ((size_t)(bj * BM + srow)) * DIMS + qq * 16;

  // --- fragment read offsets (bytes; verified zero-conflict swizzle) ---
  int laneq = lane & 15, g = lane >> 4;
  int fcB = (g ^ ((laneq >> 1) & 3)) * 16;           // swizzled 16B chunk slot
  int aOffB = (wr * 128 + laneq) * 64 + fcB;
  int bOffB = 16384 + (nc * 64 + laneq) * 64 + fcB;

  i32x4 aU[4], aV[4], bR[4];
  i32x4 sA0, sA1, sB0, sB1;                          // staging registers

  #define LOADR(T)                                                            \
    do {                                                                      \
      sA0 = *(const i32x4*)(gA + (size_t)(T) * 64);                           \
      sA1 = *(const i32x4*)(gA + (size_t)128 * DIMS + (size_t)(T) * 64);      \
      sB0 = *(const i32x4*)(gB + (size_t)(T) * 64);                           \
      sB1 = *(const i32x4*)(gB + (size_t)128 * DIMS + (size_t)(T) * 64);      \
    } while (0)

  // thread's LDS slot = tid*16 (matches the gload_lds wave-linear layout)
  #define WRITE(D)                                                            \
    do {                                                                      \
      *(i32x4*)&ldsbuf[(D) + tid * 16] = sA0;                                 \
      *(i32x4*)&ldsbuf[(D) + 8192 + tid * 16] = sA1;                          \
      *(i32x4*)&ldsbuf[(D) + 16384 + tid * 16] = sB0;                         \
      *(i32x4*)&ldsbuf[(D) + 24576 + tid * 16] = sB1;                         \
    } while (0)

  #define READ_A4(DST, MB, COFF)                                              \
    _Pragma("unroll")                                                         \
    for (int m = 0; m < 4; m++)                                               \
      DST[m] = *(const i32x4*)&ldsbuf[(COFF) + aOffB + ((MB) + m) * 1024];
  #define READ_B4(DST, COFF)                                                  \
    _Pragma("unroll")                                                         \
    for (int n = 0; n < 4; n++)                                               \
      DST[n] = *(const i32x4*)&ldsbuf[(COFF) + bOffB + n * 1024];

  #define MFMA16(MB, AR, BR)                                                  \
    __builtin_amdgcn_s_setprio(1);                                            \
    _Pragma("unroll")                                                         \
    for (int m = 0; m < 4; m++)                                               \
      _Pragma("unroll")                                                       \
      for (int n = 0; n < 4; n++)                                             \
        acc[(MB) + m][n] = __builtin_amdgcn_mfma_i32_16x16x64_i8(             \
            AR[m], BR[n], acc[(MB) + m][n], 0, 0, 0);                         \
    __builtin_amdgcn_s_setprio(0);

  #define SB __builtin_amdgcn_sched_barrier(0);

  #define TILE_BODY(CUR)                                                      \
    do {                                                                      \
      READ_B4(bR, CUR)                                                        \
      READ_A4(aU, 0, CUR)                                                     \
      MFMA16(0, aU, bR)                                                       \
      READ_A4(aV, 4, CUR)                                                     \
      MFMA16(4, aV, bR)                                                       \
    } while (0)

  // prologue: tile 0 -> regs -> set 0; tile 1 -> regs (pending)
  LOADR(0);
  WRITE(0);                 // compiler inserts vmcnt wait before the stores
  LOADR(1);
  asm volatile("s_waitcnt lgkmcnt(0)" ::: "memory");
  SB
  __builtin_amdgcn_s_barrier();
  SB

  int cur = 0, dst = 32768;
  #pragma unroll 1
  for (int kt = 0; kt <= 30; ++kt) {
    TILE_BODY(cur);         // reads cur + MFMA (compiler-scheduled interior)
    WRITE(dst);             // tile kt+1 regs -> idle set (vmcnt waited here;
                            // loads were issued a full tile earlier)
    if (kt < 30) LOADR(kt + 2);
    asm volatile("s_waitcnt lgkmcnt(0)" ::: "memory");  // drain ds_writes
    SB
    __builtin_amdgcn_s_barrier();                       // publish tile kt+1
    SB
    cur ^= 32768;
    dst ^= 32768;
  }
  TILE_BODY(cur);           // tile 31

  // ---- fused masked reduction (r12-identical) ----
  // acc[m][n][r] = Gq[bi*256 + wr*128 + m*16 + g*4 + r]
  //                  [bj*256 + nc*64  + n*16 + laneq]
  int tcol[4];
  float tcr[4];
  #pragma unroll
  for (int n = 0; n < 4; n++) {
    int idx = bj * BM + nc * 64 + n * 16 + laneq;
    tcol[n] = tgt[idx];
    tcr[n] = recip[idx];
  }
  int rbase = bi * BM + wr * 128 + g * 4;

  #pragma unroll
  for (int m = 0; m < 8; m++) {
    #pragma unroll
    for (int r = 0; r < 4; r++) {
      int grow = rbase + m * 16 + r;
      int trow = tgt[grow];
      float rrw = recip[grow];
      float ap = -__builtin_inff(), an = __builtin_inff();
      #pragma unroll
      for (int n = 0; n < 4; n++) {
        float d = -(float)acc[m][n][r] * rrw * tcr[n];
        bool same = (trow == tcol[n]);
        ap = same ? fmaxf(ap, d) : ap;
        an = same ? an : fminf(an, d);
      }
      #pragma unroll
      for (int s = 1; s < 16; s <<= 1) {
        ap = fmaxf(ap, __shfl_xor(ap, s));
        an = fminf(an, __shfl_xor(an, s));
      }
      if (laneq == 0) {
        atomicMaxF(&dap[grow], ap);
        atomicMinF(&dan[grow], an);
      }
    }
  }
  #undef LOADR
  #undef WRITE
  #undef READ_A4
  #undef READ_B4
  #undef MFMA16
  #undef SB
  #undef TILE_BODY
}

// ---------------- final loss ----------------
__global__ __launch_bounds__(256) void loss_kernel(const float* __restrict__ dap,
                                                   const float* __restrict__ dan,
                                                   float* __restrict__ out) {
  int t = threadIdx.x;
  float s = 0.f;
  for (int i = t; i < NROWS; i += 256) {
    float v = dap[i] - dan[i] + MARGIN_F;
    s += v > 0.f ? v : 0.f;
  }
  #pragma unroll
  for (int sh = 1; sh < 64; sh <<= 1) s += __shfl_xor(s, sh);
  __shared__ float ws[4];
  if ((t & 63) == 0) ws[t >> 6] = s;
  __syncthreads();
  if (t == 0) out[0] = (ws[0] + ws[1] + ws[2] + ws[3]) * (1.0f / (float)NROWS);
}

extern "C" void kernel_launch(void* const* d_in, const int* in_sizes, int n_in,
                              void* d_out, int out_size, void* d_ws, size_t ws_size,
                              hipStream_t stream) {
  const float* inputs = (const float*)d_in[0];
  const int* targets = (const int*)d_in[1];
  char* l2q = (char*)d_ws;
  float* recip = (float*)((char*)d_ws + (size_t)NROWS * DIMS);
  float* dap = recip + NROWS;
  float* dan = dap + NROWS;
  float* out = (float*)d_out;

  hipLaunchKernelGGL(norm_kernel, dim3(NROWS), dim3(256), 0, stream,
                     inputs, l2q, recip, dap, dan);
  hipLaunchKernelGGL(gemm_reduce_kernel, dim3(NTB * NTB), dim3(512), 0, stream,
                     l2q, targets, recip, dap, dan);
  hipLaunchKernelGGL(loss_kernel, dim3(1), dim3(256), 0, stream, dap, dan, out);
}